// Round 18
// baseline (423.861 us; speedup 1.0000x reference)
//
#include <hip/hip_runtime.h>
#include <math.h>

#define NEGV -9000000000000000.0f
#define WPB 16  // waves per block
#define NTHR 1024

// Packed W in LDS: WL[r][k][e] (float4) = W[r][e][4k..4k+3].
// Lane e reads WL[(r*16+k)*64+e]: 64 lanes stride 16B contiguous ->
// conflict-free ds_read_b128. xb = per-wave x staging.
struct LdsW {
  float4 w[8 * 16 * 64];  // 128 KB
  float xb[WPB][64];      // 4 KB
};

__device__ __forceinline__ float wave_sum(float v) {
#pragma unroll
  for (int m = 32; m; m >>= 1) v += __shfl_xor(v, m, 64);
  return v;
}

__device__ __forceinline__ int rl(int v, int l) {
  return __builtin_amdgcn_readlane(v, l);
}

__device__ __forceinline__ void stage_W(float4* wl, const float* __restrict__ W) {
  const float4* Wg = (const float4*)W;
  for (int f = threadIdx.x; f < 8192; f += NTHR) {
    float4 v = Wg[f];  // coalesced global
    int r = f >> 10, e = (f >> 4) & 63, k = f & 15;
    wl[(((r << 4) + k) << 6) + e] = v;
  }
  __syncthreads();
}

// Wave-uniform loads of x[32..63] (8 float4) -> SGPRs (s_load).
__device__ __forceinline__ void load_xu_hi(const float* __restrict__ emb, int nb,
                                           float4 xu[8]) {
  const float4* xg = (const float4*)(emb + ((size_t)nb << 6) + 32);
#pragma unroll
  for (int j = 0; j < 8; ++j) xu[j] = xg[j];
}

// Wave-uniform loads of the full x row (16 float4).
__device__ __forceinline__ void load_xu_full(const float* __restrict__ emb, int nb,
                                             float4 xu[16]) {
  const float4* xg = (const float4*)(emb + ((size_t)nb << 6));
#pragma unroll
  for (int j = 0; j < 16; ++j) xu[j] = xg[j];
}

// y = tanh(sum_d W[r][lane][d] * xu[d]); W row from LDS, x preloaded uniform.
// Same values, same d-ascending fmaf chain as all prior rounds -> bit-exact.
__device__ __forceinline__ float transform_pre(const float4 xu[16], int r, int lane,
                                               const float4* wl) {
  const float4* wr = wl + (r << 10) + lane;
  float acc = 0.f;
#pragma unroll
  for (int k = 0; k < 16; ++k) {
    float4 w = wr[k << 6];
    acc = fmaf(w.x, xu[k].x, acc);
    acc = fmaf(w.y, xu[k].y, acc);
    acc = fmaf(w.z, xu[k].z, acc);
    acc = fmaf(w.w, xu[k].w, acc);
  }
  return tanhf(acc);
}

// Relation-sorted order (stable) for this task's 64 neighbors.
__device__ __forceinline__ void sort_order(int lane, int nbr, int rel, int& order,
                                           int& srt_nb, int& srt_r) {
  int myrank = 0, basec = 0;
  unsigned long long ltmask = (1ull << lane) - 1ull;
#pragma unroll
  for (int rr = 0; rr < 8; ++rr) {
    unsigned long long m = __ballot(rel == rr);
    if (rel == rr) myrank = basec + (int)__popcll(m & ltmask);
    basec += (int)__popcll(m);
  }
  order = __builtin_amdgcn_ds_permute(myrank << 2, lane);
  srt_nb = __shfl(nbr, order, 64);
  srt_r = __shfl(rel, order, 64);
}

// ---- R13-proven score step: W cached+pinned in VGPRs, hybrid LDS/SMEM x
// broadcast, 1-ahead prefetch. Bit-exact.
__device__ __forceinline__ void score_step(int pos, int pend, int lane,
                                           const float4* wl, float* xbuf,
                                           const float* __restrict__ emb, int srt_r,
                                           int srt_nb, int order, float u_e,
                                           float4 wv[16], int& rcur, float& xv,
                                           float& s_mine, float4 xu[8]) {
  int r = rl(srt_r, pos);
  if (r != rcur) {
    const float4* wr = wl + (r << 10) + lane;
#pragma unroll
    for (int k = 0; k < 16; ++k) wv[k] = wr[k << 6];
#pragma unroll
    for (int k = 0; k < 16; ++k)
      asm volatile("" : "+v"(wv[k].x), "+v"(wv[k].y), "+v"(wv[k].z), "+v"(wv[k].w));
    rcur = r;
  }
  int nbn = (pos < pend - 1) ? rl(srt_nb, pos + 1) : 0;
  __builtin_amdgcn_wave_barrier();
  xbuf[lane] = xv;
  __builtin_amdgcn_wave_barrier();
  float xnext = 0.f;
  if (pos < pend - 1) xnext = emb[((size_t)nbn << 6) + lane];
  asm volatile("s_waitcnt lgkmcnt(0)" ::: "memory");  // ds_write + xu s_loads
  __builtin_amdgcn_wave_barrier();
  float acc = 0.f;
#pragma unroll
  for (int k = 0; k < 8; ++k) {
    float4 x = *(const float4*)(xbuf + 4 * k);
    acc = fmaf(wv[k].x, x.x, acc);
    acc = fmaf(wv[k].y, x.y, acc);
    acc = fmaf(wv[k].z, x.z, acc);
    acc = fmaf(wv[k].w, x.w, acc);
  }
#pragma unroll
  for (int k = 8; k < 16; ++k) {
    acc = fmaf(wv[k].x, xu[k - 8].x, acc);
    acc = fmaf(wv[k].y, xu[k - 8].y, acc);
    acc = fmaf(wv[k].z, xu[k - 8].z, acc);
    acc = fmaf(wv[k].w, xu[k - 8].w, acc);
  }
  if (pos < pend - 1) load_xu_hi(emb, nbn, xu);
  float y = tanhf(acc);
  float totv = wave_sum(u_e * y);
  int n = rl(order, pos);
  if (lane == n) s_mine = totv * (1.0f / 64.0f);
  xv = xnext;
}

// Masked softmax over 64 scores, top-8 (value desc, index asc), second masked
// softmax. Bit-exact.
__device__ __forceinline__ void topsel_core(float s_mine, int lane, int seli[8],
                                            float wout[8]) {
  float sv = (s_mine == 0.0f) ? NEGV : s_mine;
  float mx = sv;
#pragma unroll
  for (int m = 32; m; m >>= 1) mx = fmaxf(mx, __shfl_xor(mx, m, 64));
  float p = expf(sv - mx);
  float Z = wave_sum(p);
  p /= Z;
  float v = p;
  int vi = lane;
  float selv[8];
#pragma unroll
  for (int j = 0; j < 8; ++j) {
    float bv = v;
    int bi = vi;
#pragma unroll
    for (int m = 1; m < 64; m <<= 1) {
      float ov = __shfl_xor(bv, m, 64);
      int oi = __shfl_xor(bi, m, 64);
      if (ov > bv || (ov == bv && oi < bi)) { bv = ov; bi = oi; }
    }
    selv[j] = bv;
    seli[j] = bi;
    if (lane == bi) v = -__builtin_inff();
  }
  float m8 = -__builtin_inff();
#pragma unroll
  for (int j = 0; j < 8; ++j) {
    float tt = (selv[j] == 0.f) ? NEGV : selv[j];
    selv[j] = tt;
    m8 = fmaxf(m8, tt);
  }
  float Z8 = 0.f;
#pragma unroll
  for (int j = 0; j < 8; ++j) {
    selv[j] = expf(selv[j] - m8);
    Z8 += selv[j];
  }
#pragma unroll
  for (int j = 0; j < 8; ++j) wout[j] = selv[j] / Z8;
}

// ---- user embedding: 4 waves/block, wave = one batch element ----
__global__ __launch_bounds__(256) void k_user(const int* __restrict__ ui,
                                              const float* __restrict__ emb,
                                              const int* __restrict__ clicked,
                                              const float* __restrict__ numc, int hist,
                                              float* __restrict__ user_emb, int ntask) {
  int w = threadIdx.x >> 6, lane = threadIdx.x & 63;
  int b = blockIdx.x * 4 + w;
  if (b >= ntask) return;
  int u = ui[b];
  float acc = 0.f;
  for (int h = 0; h < hist; ++h) {
    int it = clicked[u * hist + h];
    acc += emb[((size_t)it << 6) + lane];
  }
  user_emb[((size_t)b << 6) + lane] = acc * (1.0f / numc[u]);
}

// ---- hop0 phase 1: one wave per (task, quarter). 4096 waves = 16/CU =
// hop1's proven density. Verbatim R13 score loop over 16 sorted positions;
// writes the sparse partial score vector to global.
__global__ __launch_bounds__(NTHR, 4) void k_score0(
    const int* __restrict__ ii, const float* __restrict__ emb,
    const float* __restrict__ W, const int* __restrict__ adjE,
    const int* __restrict__ adjR, const float* __restrict__ user_emb,
    float* __restrict__ spart, int ntask) {
  __shared__ LdsW S;
  stage_W(S.w, W);
  int w = threadIdx.x >> 6, lane = threadIdx.x & 63;
  int gw = blockIdx.x * WPB + w;  // gw = t*4 + q
  if (gw >= ntask * 4) return;
  int t = gw >> 2, q = gw & 3;
  int eid = ii[t];
  int nbr = adjE[((size_t)eid << 6) + lane];
  int rel = adjR[((size_t)eid << 6) + lane];
  float u_e = user_emb[((size_t)t << 6) + lane];
  int order, srt_nb, srt_r;
  sort_order(lane, nbr, rel, order, srt_nb, srt_r);
  int p0 = q * 16, pend = p0 + 16;
  int nb0 = rl(srt_nb, p0);
  float xv = emb[((size_t)nb0 << 6) + lane];
  float4 xu[8];
  load_xu_hi(emb, nb0, xu);
  float4 wv[16];
  int rcur = -1;
  float s_mine = 0.f;
  for (int pos = p0; pos < pend; ++pos)
    score_step(pos, pend, lane, S.w, S.xb[w], emb, srt_r, srt_nb, order, u_e, wv, rcur,
               xv, s_mine, xu);
  spart[((size_t)gw << 6) + lane] = s_mine;
}

// ---- hop0 phase 2: one wave per task. Sum the 4 partial vectors per lane
// (+0 identity -> bit-exact), topsel, R13-proven transform epilogue.
__global__ __launch_bounds__(NTHR, 4) void k_sel0(
    const int* __restrict__ ii, const float* __restrict__ emb,
    const float* __restrict__ W, const int* __restrict__ adjE,
    const int* __restrict__ adjR, const float* __restrict__ spart,
    int* __restrict__ e1, float* __restrict__ s0w, float* __restrict__ emb1,
    int ntask) {
  __shared__ LdsW S;
  stage_W(S.w, W);
  int w = threadIdx.x >> 6, lane = threadIdx.x & 63;
  int tot = gridDim.x * WPB;
  for (int t = blockIdx.x + gridDim.x * w; t < ntask; t += tot) {
    int eid = ii[t];
    int nbr = adjE[((size_t)eid << 6) + lane];
    int rel = adjR[((size_t)eid << 6) + lane];
    const float* sp = spart + ((size_t)t << 8);
    float s_mine = ((sp[lane] + sp[64 + lane]) + sp[128 + lane]) + sp[192 + lane];
    int seli[8];
    float w8[8];
    topsel_core(s_mine, lane, seli, w8);
    int nbs[8], rrs[8];
#pragma unroll
    for (int j = 0; j < 8; ++j) {
      int sj = __builtin_amdgcn_readfirstlane(seli[j]);
      nbs[j] = rl(nbr, sj);
      rrs[j] = rl(rel, sj);
    }
    if (lane == 0) {
#pragma unroll
      for (int j = 0; j < 8; ++j) {
        e1[t * 8 + j] = nbs[j];
        s0w[t * 8 + j] = w8[j];
      }
    }
    float4 xtA[16], xtB[16];
    load_xu_full(emb, nbs[0], xtA);
#pragma unroll
    for (int j = 0; j < 8; ++j) {  // fully unrolled: xc/xn static per iter
      const float4* xc = (j & 1) ? xtB : xtA;
      float4* xn = (j & 1) ? xtA : xtB;
      if (j < 7) load_xu_full(emb, nbs[j + 1], xn);  // prefetch next selected
      float y = transform_pre(xc, rrs[j], lane, S.w);
      emb1[(((size_t)t * 8 + j) << 6) + lane] = y;
    }
  }
}

// ---- hop1: score + topsel + fused aggregation (emb + labels), R13 form ----
__global__ __launch_bounds__(NTHR, 4) void k_hop1_f(
    const int* __restrict__ ui, const int* __restrict__ ii, const float* __restrict__ emb,
    const float* __restrict__ W, const int* __restrict__ adjE,
    const int* __restrict__ adjR, const float* __restrict__ labels, int np1,
    const float* __restrict__ user_emb, const int* __restrict__ e1,
    const float* __restrict__ emb1, float* __restrict__ emb1p,
    float* __restrict__ lab1p, int ntask) {
  __shared__ LdsW S;
  stage_W(S.w, W);
  int w = threadIdx.x >> 6, lane = threadIdx.x & 63;
  int wid = blockIdx.x * WPB + w;
  int tot = gridDim.x * WPB;
  for (int bj = wid; bj < ntask; bj += tot) {
    int b = bj >> 3;
    int u = ui[b];
    int item = ii[b];
    int eid = e1[bj];
    int nbr = adjE[((size_t)eid << 6) + lane];
    int rel = adjR[((size_t)eid << 6) + lane];
    float u_e = user_emb[((size_t)b << 6) + lane];
    int order, srt_nb, srt_r;
    sort_order(lane, nbr, rel, order, srt_nb, srt_r);
    int nb0 = rl(srt_nb, 0);
    float xv = emb[((size_t)nb0 << 6) + lane];
    float4 xu[8];
    load_xu_hi(emb, nb0, xu);
    float4 wv[16];
    int rcur = -1;
    float s_mine = 0.f;
    for (int pos = 0; pos < 64; ++pos)
      score_step(pos, 64, lane, S.w, S.xb[w], emb, srt_r, srt_nb, order, u_e, wv, rcur,
                 xv, s_mine, xu);
    int seli[8];
    float w8[8];
    topsel_core(s_mine, lane, seli, w8);
    int nbs[8], rrs[8];
#pragma unroll
    for (int k = 0; k < 8; ++k) {
      int sk = __builtin_amdgcn_readfirstlane(seli[k]);
      nbs[k] = rl(nbr, sk);
      rrs[k] = rl(rel, sk);
    }
    float4 xtA[16], xtB[16];
    load_xu_full(emb, nbs[0], xtA);
    float agg = 0.f, labagg = 0.f;
#pragma unroll
    for (int k = 0; k < 8; ++k) {  // fully unrolled: xc/xn static per iter
      const float4* xc = (k & 1) ? xtB : xtA;
      float4* xn = (k & 1) ? xtA : xtB;
      if (k < 7) load_xu_full(emb, nbs[k + 1], xn);  // prefetch next selected
      float y = transform_pre(xc, rrs[k], lane, S.w);
      agg = fmaf(w8[k], y, agg);
      float raw2 = labels[(size_t)u * np1 + nbs[k]];  // uniform -> scalar load
      float lab2 = (nbs[k] != item) ? raw2 : 0.5f;
      labagg = fmaf(w8[k], lab2, labagg);
    }
    float base = emb1[((size_t)bj << 6) + lane];
    emb1p[((size_t)bj << 6) + lane] = fmaxf(fmaf(agg, 0.125f, base), 0.f);
    if (lane == 0) {
      float raw1 = labels[(size_t)u * np1 + eid];
      bool hm = (eid != item);
      float l1 = hm ? raw1 : 0.5f;
      bool reset1 = (raw1 != 0.5f) && hm;
      lab1p[bj] = reset1 ? l1 : labagg;
    }
  }
}

__global__ __launch_bounds__(256) void k_final(const int* __restrict__ ii,
                                               const float* __restrict__ emb,
                                               const float* __restrict__ user_emb,
                                               const float* __restrict__ s0,
                                               const float* __restrict__ emb1,
                                               const float* __restrict__ emb1p,
                                               const float* __restrict__ lab1p,
                                               float* __restrict__ out, int bs) {
  int w = threadIdx.x >> 6, lane = threadIdx.x & 63;
  int b = blockIdx.x * 4 + w;
  if (b >= bs) return;
  int item = ii[b];
  float ue = user_emb[((size_t)b << 6) + lane];
  float agg = 0.f, aggp = 0.f, lab = 0.f;
#pragma unroll
  for (int j = 0; j < 8; ++j) {
    float s = s0[b * 8 + j];
    agg = fmaf(s, emb1[(((size_t)b * 8 + j) << 6) + lane], agg);
    aggp = fmaf(s, emb1p[(((size_t)b * 8 + j) << 6) + lane], aggp);
    lab = fmaf(s, lab1p[b * 8 + j], lab);
  }
  float e0 = emb[((size_t)item << 6) + lane];
  float h = fmaxf(fmaf(agg, 0.125f, e0), 0.f);  // relu(agg01 + emb0)
  float h2 = tanhf(fmaf(aggp, 0.125f, h));      // tanh(agg01' + emb0')
  float dot = wave_sum(ue * h2);
  if (lane == 0) {
    out[b] = 1.f / (1.f + expf(-dot));
    out[bs + b] = 1.f / (1.f + expf(-(lab - 0.5f)));
  }
}

extern "C" void kernel_launch(void* const* d_in, const int* in_sizes, int n_in, void* d_out,
                              int out_size, void* d_ws, size_t ws_size, hipStream_t stream) {
  const int* ui = (const int*)d_in[0];
  const int* ii = (const int*)d_in[1];
  const float* emb = (const float*)d_in[2];
  const float* W = (const float*)d_in[3];
  const int* adjE = (const int*)d_in[4];
  const int* adjR = (const int*)d_in[5];
  const int* clicked = (const int*)d_in[6];
  const float* numc = (const float*)d_in[7];
  const float* labels = (const float*)d_in[8];

  int bs = in_sizes[0];
  int np1 = in_sizes[2] / 64;  // n_entity + 1 (= labels row stride = offset)
  int nuser = in_sizes[7];
  int hist = in_sizes[6] / nuser;

  // workspace layout
  float* user_emb = (float*)d_ws;               // bs*64
  float* s0w = user_emb + (size_t)bs * 64;      // bs*8
  int* e1 = (int*)(s0w + (size_t)bs * 8);       // bs*8
  float* emb1 = (float*)(e1 + (size_t)bs * 8);  // bs*8*64
  float* emb1p = emb1 + (size_t)bs * 8 * 64;    // bs*8*64
  float* lab1p = emb1p + (size_t)bs * 8 * 64;   // bs*8
  float* spart = lab1p + (size_t)bs * 8;        // bs*4*64

  int nt0 = bs;      // hop0 tasks
  int nt1 = bs * 8;  // hop1 tasks

  k_user<<<(nt0 + 3) / 4, 256, 0, stream>>>(ui, emb, clicked, numc, hist, user_emb, nt0);
  k_score0<<<(nt0 * 4 + WPB - 1) / WPB, NTHR, 0, stream>>>(ii, emb, W, adjE, adjR,
                                                           user_emb, spart, nt0);
  k_sel0<<<256, NTHR, 0, stream>>>(ii, emb, W, adjE, adjR, spart, e1, s0w, emb1, nt0);
  k_hop1_f<<<256, NTHR, 0, stream>>>(ui, ii, emb, W, adjE, adjR, labels, np1, user_emb,
                                     e1, emb1, emb1p, lab1p, nt1);
  k_final<<<(nt0 + 3) / 4, 256, 0, stream>>>(ii, emb, user_emb, s0w, emb1, emb1p, lab1p,
                                             (float*)d_out, bs);
}

// Round 19
// 213.751 us; speedup vs baseline: 1.9830x; 1.9830x over previous
//
#include <hip/hip_runtime.h>
#include <math.h>

#define NEGV -9000000000000000.0f
#define WPB 16  // waves per block
#define NTHR 1024

// Packed W in LDS: WL[r][k][e] (float4) = W[r][e][4k..4k+3].
// Lane e reads WL[(r*16+k)*64+e]: 64 lanes stride 16B contiguous ->
// conflict-free ds_read_b128. xb = per-wave x staging (hop1).
struct LdsW {
  float4 w[8 * 16 * 64];  // 128 KB
  float xb[WPB][64];      // 4 KB
};

__device__ __forceinline__ float wave_sum(float v) {
#pragma unroll
  for (int m = 32; m; m >>= 1) v += __shfl_xor(v, m, 64);
  return v;
}

__device__ __forceinline__ int rl(int v, int l) {
  return __builtin_amdgcn_readlane(v, l);
}

// Broadcast lane l's value of v to all lanes via v_readlane (VALU, no DS).
__device__ __forceinline__ float lane_bcast(float v, int l) {
  return __uint_as_float(__builtin_amdgcn_readlane(__float_as_uint(v), l));
}

__device__ __forceinline__ void stage_W(float4* wl, const float* __restrict__ W) {
  const float4* Wg = (const float4*)W;
  for (int f = threadIdx.x; f < 8192; f += NTHR) {
    float4 v = Wg[f];  // coalesced global
    int r = f >> 10, e = (f >> 4) & 63, k = f & 15;
    wl[(((r << 4) + k) << 6) + e] = v;
  }
  __syncthreads();
}

// Wave-uniform loads of x[32..63] (8 float4) -> SGPRs (s_load).
__device__ __forceinline__ void load_xu_hi(const float* __restrict__ emb, int nb,
                                           float4 xu[8]) {
  const float4* xg = (const float4*)(emb + ((size_t)nb << 6) + 32);
#pragma unroll
  for (int j = 0; j < 8; ++j) xu[j] = xg[j];
}

// Wave-uniform loads of the full x row (16 float4).
__device__ __forceinline__ void load_xu_full(const float* __restrict__ emb, int nb,
                                             float4 xu[16]) {
  const float4* xg = (const float4*)(emb + ((size_t)nb << 6));
#pragma unroll
  for (int j = 0; j < 16; ++j) xu[j] = xg[j];
}

// y = tanh(sum_d W[r][lane][d] * xu[d]); W row from LDS, x preloaded uniform.
// Same values, same d-ascending fmaf chain as all prior rounds -> bit-exact.
__device__ __forceinline__ float transform_pre(const float4 xu[16], int r, int lane,
                                               const float4* wl) {
  const float4* wr = wl + (r << 10) + lane;
  float acc = 0.f;
#pragma unroll
  for (int k = 0; k < 16; ++k) {
    float4 w = wr[k << 6];
    acc = fmaf(w.x, xu[k].x, acc);
    acc = fmaf(w.y, xu[k].y, acc);
    acc = fmaf(w.z, xu[k].z, acc);
    acc = fmaf(w.w, xu[k].w, acc);
  }
  return tanhf(acc);
}

// Relation-sorted order (stable) for this task's 64 neighbors.
__device__ __forceinline__ void sort_order(int lane, int nbr, int rel, int& order,
                                           int& srt_nb, int& srt_r) {
  int myrank = 0, basec = 0;
  unsigned long long ltmask = (1ull << lane) - 1ull;
#pragma unroll
  for (int rr = 0; rr < 8; ++rr) {
    unsigned long long m = __ballot(rel == rr);
    if (rel == rr) myrank = basec + (int)__popcll(m & ltmask);
    basec += (int)__popcll(m);
  }
  order = __builtin_amdgcn_ds_permute(myrank << 2, lane);
  srt_nb = __shfl(nbr, order, 64);
  srt_r = __shfl(rel, order, 64);
}

// ---- R13-proven hop1 score step: W cached+pinned in VGPRs, hybrid LDS/SMEM
// x broadcast, 1-ahead prefetch. Bit-exact.
__device__ __forceinline__ void score_step(int pos, int pend, int lane,
                                           const float4* wl, float* xbuf,
                                           const float* __restrict__ emb, int srt_r,
                                           int srt_nb, int order, float u_e,
                                           float4 wv[16], int& rcur, float& xv,
                                           float& s_mine, float4 xu[8]) {
  int r = rl(srt_r, pos);
  if (r != rcur) {
    const float4* wr = wl + (r << 10) + lane;
#pragma unroll
    for (int k = 0; k < 16; ++k) wv[k] = wr[k << 6];
#pragma unroll
    for (int k = 0; k < 16; ++k)
      asm volatile("" : "+v"(wv[k].x), "+v"(wv[k].y), "+v"(wv[k].z), "+v"(wv[k].w));
    rcur = r;
  }
  int nbn = (pos < pend - 1) ? rl(srt_nb, pos + 1) : 0;
  __builtin_amdgcn_wave_barrier();
  xbuf[lane] = xv;
  __builtin_amdgcn_wave_barrier();
  float xnext = 0.f;
  if (pos < pend - 1) xnext = emb[((size_t)nbn << 6) + lane];
  asm volatile("s_waitcnt lgkmcnt(0)" ::: "memory");  // ds_write + xu s_loads
  __builtin_amdgcn_wave_barrier();
  float acc = 0.f;
#pragma unroll
  for (int k = 0; k < 8; ++k) {
    float4 x = *(const float4*)(xbuf + 4 * k);
    acc = fmaf(wv[k].x, x.x, acc);
    acc = fmaf(wv[k].y, x.y, acc);
    acc = fmaf(wv[k].z, x.z, acc);
    acc = fmaf(wv[k].w, x.w, acc);
  }
#pragma unroll
  for (int k = 8; k < 16; ++k) {
    acc = fmaf(wv[k].x, xu[k - 8].x, acc);
    acc = fmaf(wv[k].y, xu[k - 8].y, acc);
    acc = fmaf(wv[k].z, xu[k - 8].z, acc);
    acc = fmaf(wv[k].w, xu[k - 8].w, acc);
  }
  if (pos < pend - 1) load_xu_hi(emb, nbn, xu);
  float y = tanhf(acc);
  float totv = wave_sum(u_e * y);
  int n = rl(order, pos);
  if (lane == n) s_mine = totv * (1.0f / 64.0f);
  xv = xnext;
}

// Masked softmax over 64 scores, top-8 (value desc, index asc), second masked
// softmax. Bit-exact.
__device__ __forceinline__ void topsel_core(float s_mine, int lane, int seli[8],
                                            float wout[8]) {
  float sv = (s_mine == 0.0f) ? NEGV : s_mine;
  float mx = sv;
#pragma unroll
  for (int m = 32; m; m >>= 1) mx = fmaxf(mx, __shfl_xor(mx, m, 64));
  float p = expf(sv - mx);
  float Z = wave_sum(p);
  p /= Z;
  float v = p;
  int vi = lane;
  float selv[8];
#pragma unroll
  for (int j = 0; j < 8; ++j) {
    float bv = v;
    int bi = vi;
#pragma unroll
    for (int m = 1; m < 64; m <<= 1) {
      float ov = __shfl_xor(bv, m, 64);
      int oi = __shfl_xor(bi, m, 64);
      if (ov > bv || (ov == bv && oi < bi)) { bv = ov; bi = oi; }
    }
    selv[j] = bv;
    seli[j] = bi;
    if (lane == bi) v = -__builtin_inff();
  }
  float m8 = -__builtin_inff();
#pragma unroll
  for (int j = 0; j < 8; ++j) {
    float tt = (selv[j] == 0.f) ? NEGV : selv[j];
    selv[j] = tt;
    m8 = fmaxf(m8, tt);
  }
  float Z8 = 0.f;
#pragma unroll
  for (int j = 0; j < 8; ++j) {
    selv[j] = expf(selv[j] - m8);
    Z8 += selv[j];
  }
#pragma unroll
  for (int j = 0; j < 8; ++j) wout[j] = selv[j] / Z8;
}

// ---- user embedding: 4 waves/block, wave = one batch element ----
__global__ __launch_bounds__(256) void k_user(const int* __restrict__ ui,
                                              const float* __restrict__ emb,
                                              const int* __restrict__ clicked,
                                              const float* __restrict__ numc, int hist,
                                              float* __restrict__ user_emb, int ntask) {
  int w = threadIdx.x >> 6, lane = threadIdx.x & 63;
  int b = blockIdx.x * 4 + w;
  if (b >= ntask) return;
  int u = ui[b];
  float acc = 0.f;
  for (int h = 0; h < hist; ++h) {
    int it = clicked[u * hist + h];
    acc += emb[((size_t)it << 6) + lane];
  }
  user_emb[((size_t)b << 6) + lane] = acc * (1.0f / numc[u]);
}

// ---- hop0: R13 control flow (interleaved map, constant-bound 0..64 loop —
// the only form that never spills), but LATENCY-optimized matvec for the
// 1-wave/SIMD regime: all-readlane x broadcast (R7-proven), zero per-step
// DS/fence/s_load. W relation-cached in wv. Bit-exact values & chain order.
__global__ __launch_bounds__(NTHR, 4) void k_hop0_f(
    const int* __restrict__ ii, const float* __restrict__ emb,
    const float* __restrict__ W, const int* __restrict__ adjE,
    const int* __restrict__ adjR, const float* __restrict__ user_emb,
    int* __restrict__ e1, float* __restrict__ s0w, float* __restrict__ emb1,
    int ntask) {
  __shared__ LdsW S;
  stage_W(S.w, W);
  int w = threadIdx.x >> 6, lane = threadIdx.x & 63;
  int tot = gridDim.x * WPB;
  for (int t = blockIdx.x + gridDim.x * w; t < ntask; t += tot) {
    int eid = ii[t];
    int nbr = adjE[((size_t)eid << 6) + lane];
    int rel = adjR[((size_t)eid << 6) + lane];
    float u_e = user_emb[((size_t)t << 6) + lane];
    int order, srt_nb, srt_r;
    sort_order(lane, nbr, rel, order, srt_nb, srt_r);
    int nb0 = rl(srt_nb, 0);
    float xv = emb[((size_t)nb0 << 6) + lane];  // prefetch first row
    float4 wv[16];
    int rcur = -1;
    float s_mine = 0.f;
    for (int pos = 0; pos < 64; ++pos) {
      int r = rl(srt_r, pos);
      if (r != rcur) {  // wave-uniform; ~7-8 reloads per task
        const float4* wr = S.w + (r << 10) + lane;
#pragma unroll
        for (int k = 0; k < 16; ++k) wv[k] = wr[k << 6];
#pragma unroll
        for (int k = 0; k < 16; ++k)
          asm volatile("" : "+v"(wv[k].x), "+v"(wv[k].y), "+v"(wv[k].z), "+v"(wv[k].w));
        rcur = r;
      }
      float xnext = 0.f;
      if (pos < 63) {  // prefetch next row; latency hidden by this matvec
        int nbn = rl(srt_nb, pos + 1);
        xnext = emb[((size_t)nbn << 6) + lane];
      }
      // fence-free matvec: x broadcast via readlane (VALU), no DS/SMEM
      float acc = 0.f;
#pragma unroll
      for (int k = 0; k < 16; ++k) {
        acc = fmaf(wv[k].x, lane_bcast(xv, 4 * k + 0), acc);
        acc = fmaf(wv[k].y, lane_bcast(xv, 4 * k + 1), acc);
        acc = fmaf(wv[k].z, lane_bcast(xv, 4 * k + 2), acc);
        acc = fmaf(wv[k].w, lane_bcast(xv, 4 * k + 3), acc);
      }
      float y = tanhf(acc);
      float totv = wave_sum(u_e * y);
      int n = rl(order, pos);
      if (lane == n) s_mine = totv * (1.0f / 64.0f);
      xv = xnext;
    }
    int seli[8];
    float w8[8];
    topsel_core(s_mine, lane, seli, w8);
    int nbs[8], rrs[8];
#pragma unroll
    for (int j = 0; j < 8; ++j) {
      int sj = __builtin_amdgcn_readfirstlane(seli[j]);
      nbs[j] = rl(nbr, sj);
      rrs[j] = rl(rel, sj);
    }
    if (lane == 0) {
#pragma unroll
      for (int j = 0; j < 8; ++j) {
        e1[t * 8 + j] = nbs[j];
        s0w[t * 8 + j] = w8[j];
      }
    }
    // transforms: preload all 8 x rows (8 loads in flight), then 8
    // fence-free readlane matvecs with W rows read per-k from LDS.
    float xv8[8];
#pragma unroll
    for (int j = 0; j < 8; ++j) xv8[j] = emb[((size_t)nbs[j] << 6) + lane];
#pragma unroll
    for (int j = 0; j < 8; ++j) {
      const float4* wr = S.w + (rrs[j] << 10) + lane;
      float acc = 0.f;
#pragma unroll
      for (int k = 0; k < 16; ++k) {
        float4 wq = wr[k << 6];
        acc = fmaf(wq.x, lane_bcast(xv8[j], 4 * k + 0), acc);
        acc = fmaf(wq.y, lane_bcast(xv8[j], 4 * k + 1), acc);
        acc = fmaf(wq.z, lane_bcast(xv8[j], 4 * k + 2), acc);
        acc = fmaf(wq.w, lane_bcast(xv8[j], 4 * k + 3), acc);
      }
      emb1[(((size_t)t * 8 + j) << 6) + lane] = tanhf(acc);
    }
  }
}

// ---- hop1: score + topsel + fused aggregation (emb + labels), R13 form ----
__global__ __launch_bounds__(NTHR, 4) void k_hop1_f(
    const int* __restrict__ ui, const int* __restrict__ ii, const float* __restrict__ emb,
    const float* __restrict__ W, const int* __restrict__ adjE,
    const int* __restrict__ adjR, const float* __restrict__ labels, int np1,
    const float* __restrict__ user_emb, const int* __restrict__ e1,
    const float* __restrict__ emb1, float* __restrict__ emb1p,
    float* __restrict__ lab1p, int ntask) {
  __shared__ LdsW S;
  stage_W(S.w, W);
  int w = threadIdx.x >> 6, lane = threadIdx.x & 63;
  int wid = blockIdx.x * WPB + w;
  int tot = gridDim.x * WPB;
  for (int bj = wid; bj < ntask; bj += tot) {
    int b = bj >> 3;
    int u = ui[b];
    int item = ii[b];
    int eid = e1[bj];
    int nbr = adjE[((size_t)eid << 6) + lane];
    int rel = adjR[((size_t)eid << 6) + lane];
    float u_e = user_emb[((size_t)b << 6) + lane];
    int order, srt_nb, srt_r;
    sort_order(lane, nbr, rel, order, srt_nb, srt_r);
    int nb0 = rl(srt_nb, 0);
    float xv = emb[((size_t)nb0 << 6) + lane];
    float4 xu[8];
    load_xu_hi(emb, nb0, xu);
    float4 wv[16];
    int rcur = -1;
    float s_mine = 0.f;
    for (int pos = 0; pos < 64; ++pos)
      score_step(pos, 64, lane, S.w, S.xb[w], emb, srt_r, srt_nb, order, u_e, wv, rcur,
                 xv, s_mine, xu);
    int seli[8];
    float w8[8];
    topsel_core(s_mine, lane, seli, w8);
    int nbs[8], rrs[8];
#pragma unroll
    for (int k = 0; k < 8; ++k) {
      int sk = __builtin_amdgcn_readfirstlane(seli[k]);
      nbs[k] = rl(nbr, sk);
      rrs[k] = rl(rel, sk);
    }
    float4 xtA[16], xtB[16];
    load_xu_full(emb, nbs[0], xtA);
    float agg = 0.f, labagg = 0.f;
#pragma unroll
    for (int k = 0; k < 8; ++k) {  // fully unrolled: xc/xn static per iter
      const float4* xc = (k & 1) ? xtB : xtA;
      float4* xn = (k & 1) ? xtA : xtB;
      if (k < 7) load_xu_full(emb, nbs[k + 1], xn);  // prefetch next selected
      float y = transform_pre(xc, rrs[k], lane, S.w);
      agg = fmaf(w8[k], y, agg);
      float raw2 = labels[(size_t)u * np1 + nbs[k]];  // uniform -> scalar load
      float lab2 = (nbs[k] != item) ? raw2 : 0.5f;
      labagg = fmaf(w8[k], lab2, labagg);
    }
    float base = emb1[((size_t)bj << 6) + lane];
    emb1p[((size_t)bj << 6) + lane] = fmaxf(fmaf(agg, 0.125f, base), 0.f);
    if (lane == 0) {
      float raw1 = labels[(size_t)u * np1 + eid];
      bool hm = (eid != item);
      float l1 = hm ? raw1 : 0.5f;
      bool reset1 = (raw1 != 0.5f) && hm;
      lab1p[bj] = reset1 ? l1 : labagg;
    }
  }
}

__global__ __launch_bounds__(256) void k_final(const int* __restrict__ ii,
                                               const float* __restrict__ emb,
                                               const float* __restrict__ user_emb,
                                               const float* __restrict__ s0,
                                               const float* __restrict__ emb1,
                                               const float* __restrict__ emb1p,
                                               const float* __restrict__ lab1p,
                                               float* __restrict__ out, int bs) {
  int w = threadIdx.x >> 6, lane = threadIdx.x & 63;
  int b = blockIdx.x * 4 + w;
  if (b >= bs) return;
  int item = ii[b];
  float ue = user_emb[((size_t)b << 6) + lane];
  float agg = 0.f, aggp = 0.f, lab = 0.f;
#pragma unroll
  for (int j = 0; j < 8; ++j) {
    float s = s0[b * 8 + j];
    agg = fmaf(s, emb1[(((size_t)b * 8 + j) << 6) + lane], agg);
    aggp = fmaf(s, emb1p[(((size_t)b * 8 + j) << 6) + lane], aggp);
    lab = fmaf(s, lab1p[b * 8 + j], lab);
  }
  float e0 = emb[((size_t)item << 6) + lane];
  float h = fmaxf(fmaf(agg, 0.125f, e0), 0.f);  // relu(agg01 + emb0)
  float h2 = tanhf(fmaf(aggp, 0.125f, h));      // tanh(agg01' + emb0')
  float dot = wave_sum(ue * h2);
  if (lane == 0) {
    out[b] = 1.f / (1.f + expf(-dot));
    out[bs + b] = 1.f / (1.f + expf(-(lab - 0.5f)));
  }
}

extern "C" void kernel_launch(void* const* d_in, const int* in_sizes, int n_in, void* d_out,
                              int out_size, void* d_ws, size_t ws_size, hipStream_t stream) {
  const int* ui = (const int*)d_in[0];
  const int* ii = (const int*)d_in[1];
  const float* emb = (const float*)d_in[2];
  const float* W = (const float*)d_in[3];
  const int* adjE = (const int*)d_in[4];
  const int* adjR = (const int*)d_in[5];
  const int* clicked = (const int*)d_in[6];
  const float* numc = (const float*)d_in[7];
  const float* labels = (const float*)d_in[8];

  int bs = in_sizes[0];
  int np1 = in_sizes[2] / 64;  // n_entity + 1 (= labels row stride = offset)
  int nuser = in_sizes[7];
  int hist = in_sizes[6] / nuser;

  // workspace layout
  float* user_emb = (float*)d_ws;               // bs*64
  float* s0w = user_emb + (size_t)bs * 64;      // bs*8
  int* e1 = (int*)(s0w + (size_t)bs * 8);       // bs*8
  float* emb1 = (float*)(e1 + (size_t)bs * 8);  // bs*8*64
  float* emb1p = emb1 + (size_t)bs * 8 * 64;    // bs*8*64
  float* lab1p = emb1p + (size_t)bs * 8 * 64;   // bs*8

  int nt0 = bs;      // hop0 tasks
  int nt1 = bs * 8;  // hop1 tasks

  k_user<<<(nt0 + 3) / 4, 256, 0, stream>>>(ui, emb, clicked, numc, hist, user_emb, nt0);
  k_hop0_f<<<256, NTHR, 0, stream>>>(ii, emb, W, adjE, adjR, user_emb, e1, s0w, emb1,
                                     nt0);
  k_hop1_f<<<256, NTHR, 0, stream>>>(ui, ii, emb, W, adjE, adjR, labels, np1, user_emb,
                                     e1, emb1, emb1p, lab1p, nt1);
  k_final<<<(nt0 + 3) / 4, 256, 0, stream>>>(ii, emb, user_emb, s0w, emb1, emb1p, lab1p,
                                             (float*)d_out, bs);
}

// Round 20
// 212.941 us; speedup vs baseline: 1.9905x; 1.0038x over previous
//
#include <hip/hip_runtime.h>
#include <math.h>

#define NEGV -9000000000000000.0f
#define WPB 16  // waves per block
#define NTHR 1024

// Packed W in LDS: WL[r][k][e] (float4) = W[r][e][4k..4k+3].
// Lane e reads WL[(r*16+k)*64+e]: 64 lanes stride 16B contiguous ->
// conflict-free ds_read_b128. xb = per-wave x staging (hop1).
struct LdsW {
  float4 w[8 * 16 * 64];  // 128 KB
  float xb[WPB][64];      // 4 KB
};

__device__ __forceinline__ float wave_sum(float v) {
#pragma unroll
  for (int m = 32; m; m >>= 1) v += __shfl_xor(v, m, 64);
  return v;
}

__device__ __forceinline__ int rl(int v, int l) {
  return __builtin_amdgcn_readlane(v, l);
}

// Broadcast lane l's value of v to all lanes via v_readlane (VALU, no DS).
__device__ __forceinline__ float lane_bcast(float v, int l) {
  return __uint_as_float(__builtin_amdgcn_readlane(__float_as_uint(v), l));
}

__device__ __forceinline__ void stage_W(float4* wl, const float* __restrict__ W) {
  const float4* Wg = (const float4*)W;
  for (int f = threadIdx.x; f < 8192; f += NTHR) {
    float4 v = Wg[f];  // coalesced global
    int r = f >> 10, e = (f >> 4) & 63, k = f & 15;
    wl[(((r << 4) + k) << 6) + e] = v;
  }
  __syncthreads();
}

// Wave-uniform loads of x[32..63] (8 float4) -> SGPRs (s_load).
__device__ __forceinline__ void load_xu_hi(const float* __restrict__ emb, int nb,
                                           float4 xu[8]) {
  const float4* xg = (const float4*)(emb + ((size_t)nb << 6) + 32);
#pragma unroll
  for (int j = 0; j < 8; ++j) xu[j] = xg[j];
}

// Wave-uniform loads of the full x row (16 float4).
__device__ __forceinline__ void load_xu_full(const float* __restrict__ emb, int nb,
                                             float4 xu[16]) {
  const float4* xg = (const float4*)(emb + ((size_t)nb << 6));
#pragma unroll
  for (int j = 0; j < 16; ++j) xu[j] = xg[j];
}

// y = tanh(sum_d W[r][lane][d] * xu[d]); W row from LDS, x preloaded uniform.
// Same values, same d-ascending fmaf chain as all prior rounds -> bit-exact.
__device__ __forceinline__ float transform_pre(const float4 xu[16], int r, int lane,
                                               const float4* wl) {
  const float4* wr = wl + (r << 10) + lane;
  float acc = 0.f;
#pragma unroll
  for (int k = 0; k < 16; ++k) {
    float4 w = wr[k << 6];
    acc = fmaf(w.x, xu[k].x, acc);
    acc = fmaf(w.y, xu[k].y, acc);
    acc = fmaf(w.z, xu[k].z, acc);
    acc = fmaf(w.w, xu[k].w, acc);
  }
  return tanhf(acc);
}

// Relation-sorted order (stable) for this task's 64 neighbors.
__device__ __forceinline__ void sort_order(int lane, int nbr, int rel, int& order,
                                           int& srt_nb, int& srt_r) {
  int myrank = 0, basec = 0;
  unsigned long long ltmask = (1ull << lane) - 1ull;
#pragma unroll
  for (int rr = 0; rr < 8; ++rr) {
    unsigned long long m = __ballot(rel == rr);
    if (rel == rr) myrank = basec + (int)__popcll(m & ltmask);
    basec += (int)__popcll(m);
  }
  order = __builtin_amdgcn_ds_permute(myrank << 2, lane);
  srt_nb = __shfl(nbr, order, 64);
  srt_r = __shfl(rel, order, 64);
}

// Masked softmax over 64 scores, top-8 (value desc, index asc), second masked
// softmax. Bit-exact.
__device__ __forceinline__ void topsel_core(float s_mine, int lane, int seli[8],
                                            float wout[8]) {
  float sv = (s_mine == 0.0f) ? NEGV : s_mine;
  float mx = sv;
#pragma unroll
  for (int m = 32; m; m >>= 1) mx = fmaxf(mx, __shfl_xor(mx, m, 64));
  float p = expf(sv - mx);
  float Z = wave_sum(p);
  p /= Z;
  float v = p;
  int vi = lane;
  float selv[8];
#pragma unroll
  for (int j = 0; j < 8; ++j) {
    float bv = v;
    int bi = vi;
#pragma unroll
    for (int m = 1; m < 64; m <<= 1) {
      float ov = __shfl_xor(bv, m, 64);
      int oi = __shfl_xor(bi, m, 64);
      if (ov > bv || (ov == bv && oi < bi)) { bv = ov; bi = oi; }
    }
    selv[j] = bv;
    seli[j] = bi;
    if (lane == bi) v = -__builtin_inff();
  }
  float m8 = -__builtin_inff();
#pragma unroll
  for (int j = 0; j < 8; ++j) {
    float tt = (selv[j] == 0.f) ? NEGV : selv[j];
    selv[j] = tt;
    m8 = fmaxf(m8, tt);
  }
  float Z8 = 0.f;
#pragma unroll
  for (int j = 0; j < 8; ++j) {
    selv[j] = expf(selv[j] - m8);
    Z8 += selv[j];
  }
#pragma unroll
  for (int j = 0; j < 8; ++j) wout[j] = selv[j] / Z8;
}

// ---- user embedding: 4 waves/block, wave = one batch element ----
__global__ __launch_bounds__(256) void k_user(const int* __restrict__ ui,
                                              const float* __restrict__ emb,
                                              const int* __restrict__ clicked,
                                              const float* __restrict__ numc, int hist,
                                              float* __restrict__ user_emb, int ntask) {
  int w = threadIdx.x >> 6, lane = threadIdx.x & 63;
  int b = blockIdx.x * 4 + w;
  if (b >= ntask) return;
  int u = ui[b];
  float acc = 0.f;
  for (int h = 0; h < hist; ++h) {
    int it = clicked[u * hist + h];
    acc += emb[((size_t)it << 6) + lane];
  }
  user_emb[((size_t)b << 6) + lane] = acc * (1.0f / numc[u]);
}

// ---- hop0: R19 form (interleaved map, constant-bound loop, fence-free
// readlane matvec for the 1-wave/SIMD regime). Bit-exact.
__global__ __launch_bounds__(NTHR, 4) void k_hop0_f(
    const int* __restrict__ ii, const float* __restrict__ emb,
    const float* __restrict__ W, const int* __restrict__ adjE,
    const int* __restrict__ adjR, const float* __restrict__ user_emb,
    int* __restrict__ e1, float* __restrict__ s0w, float* __restrict__ emb1,
    int ntask) {
  __shared__ LdsW S;
  stage_W(S.w, W);
  int w = threadIdx.x >> 6, lane = threadIdx.x & 63;
  int tot = gridDim.x * WPB;
  for (int t = blockIdx.x + gridDim.x * w; t < ntask; t += tot) {
    int eid = ii[t];
    int nbr = adjE[((size_t)eid << 6) + lane];
    int rel = adjR[((size_t)eid << 6) + lane];
    float u_e = user_emb[((size_t)t << 6) + lane];
    int order, srt_nb, srt_r;
    sort_order(lane, nbr, rel, order, srt_nb, srt_r);
    int nb0 = rl(srt_nb, 0);
    float xv = emb[((size_t)nb0 << 6) + lane];  // prefetch first row
    float4 wv[16];
    int rcur = -1;
    float s_mine = 0.f;
    for (int pos = 0; pos < 64; ++pos) {
      int r = rl(srt_r, pos);
      if (r != rcur) {  // wave-uniform; ~7-8 reloads per task
        const float4* wr = S.w + (r << 10) + lane;
#pragma unroll
        for (int k = 0; k < 16; ++k) wv[k] = wr[k << 6];
#pragma unroll
        for (int k = 0; k < 16; ++k)
          asm volatile("" : "+v"(wv[k].x), "+v"(wv[k].y), "+v"(wv[k].z), "+v"(wv[k].w));
        rcur = r;
      }
      float xnext = 0.f;
      if (pos < 63) {  // prefetch next row; latency hidden by this matvec
        int nbn = rl(srt_nb, pos + 1);
        xnext = emb[((size_t)nbn << 6) + lane];
      }
      // fence-free matvec: x broadcast via readlane (VALU), no DS/SMEM
      float acc = 0.f;
#pragma unroll
      for (int k = 0; k < 16; ++k) {
        acc = fmaf(wv[k].x, lane_bcast(xv, 4 * k + 0), acc);
        acc = fmaf(wv[k].y, lane_bcast(xv, 4 * k + 1), acc);
        acc = fmaf(wv[k].z, lane_bcast(xv, 4 * k + 2), acc);
        acc = fmaf(wv[k].w, lane_bcast(xv, 4 * k + 3), acc);
      }
      float y = tanhf(acc);
      float totv = wave_sum(u_e * y);
      int n = rl(order, pos);
      if (lane == n) s_mine = totv * (1.0f / 64.0f);
      xv = xnext;
    }
    int seli[8];
    float w8[8];
    topsel_core(s_mine, lane, seli, w8);
    int nbs[8], rrs[8];
#pragma unroll
    for (int j = 0; j < 8; ++j) {
      int sj = __builtin_amdgcn_readfirstlane(seli[j]);
      nbs[j] = rl(nbr, sj);
      rrs[j] = rl(rel, sj);
    }
    if (lane == 0) {
#pragma unroll
      for (int j = 0; j < 8; ++j) {
        e1[t * 8 + j] = nbs[j];
        s0w[t * 8 + j] = w8[j];
      }
    }
    // transforms: preload all 8 x rows (8 loads in flight), then 8
    // fence-free readlane matvecs with W rows read per-k from LDS.
    float xv8[8];
#pragma unroll
    for (int j = 0; j < 8; ++j) xv8[j] = emb[((size_t)nbs[j] << 6) + lane];
#pragma unroll
    for (int j = 0; j < 8; ++j) {
      const float4* wr = S.w + (rrs[j] << 10) + lane;
      float acc = 0.f;
#pragma unroll
      for (int k = 0; k < 16; ++k) {
        float4 wq = wr[k << 6];
        acc = fmaf(wq.x, lane_bcast(xv8[j], 4 * k + 0), acc);
        acc = fmaf(wq.y, lane_bcast(xv8[j], 4 * k + 1), acc);
        acc = fmaf(wq.z, lane_bcast(xv8[j], 4 * k + 2), acc);
        acc = fmaf(wq.w, lane_bcast(xv8[j], 4 * k + 3), acc);
      }
      emb1[(((size_t)t * 8 + j) << 6) + lane] = tanhf(acc);
    }
  }
}

// ---- hop1: score (WRITE-AHEAD staging: x(pos+1) written to LDS at the END
// of step pos, so the start-of-step fence waits a ~1-matvec-old write instead
// of a fresh one; same-wave DS ops are in-order so single-buffer is safe)
// + topsel + fused aggregation. All values & fmaf order bit-exact.
__global__ __launch_bounds__(NTHR, 4) void k_hop1_f(
    const int* __restrict__ ui, const int* __restrict__ ii, const float* __restrict__ emb,
    const float* __restrict__ W, const int* __restrict__ adjE,
    const int* __restrict__ adjR, const float* __restrict__ labels, int np1,
    const float* __restrict__ user_emb, const int* __restrict__ e1,
    const float* __restrict__ emb1, float* __restrict__ emb1p,
    float* __restrict__ lab1p, int ntask) {
  __shared__ LdsW S;
  stage_W(S.w, W);
  int w = threadIdx.x >> 6, lane = threadIdx.x & 63;
  float* xbuf = S.xb[w];
  int wid = blockIdx.x * WPB + w;
  int tot = gridDim.x * WPB;
  for (int bj = wid; bj < ntask; bj += tot) {
    int b = bj >> 3;
    int u = ui[b];
    int item = ii[b];
    int eid = e1[bj];
    int nbr = adjE[((size_t)eid << 6) + lane];
    int rel = adjR[((size_t)eid << 6) + lane];
    float u_e = user_emb[((size_t)b << 6) + lane];
    int order, srt_nb, srt_r;
    sort_order(lane, nbr, rel, order, srt_nb, srt_r);
    // prologue: stage x(0), issue s_loads(0), issue global x(1)
    int nb0 = rl(srt_nb, 0);
    float xin = emb[((size_t)nb0 << 6) + lane];
    float4 xu[8];
    load_xu_hi(emb, nb0, xu);
    __builtin_amdgcn_wave_barrier();
    xbuf[lane] = xin;  // compiler waits vmcnt for xin before the write
    __builtin_amdgcn_wave_barrier();
    int nb1 = rl(srt_nb, 1);
    xin = emb[((size_t)nb1 << 6) + lane];
    float4 wv[16];
    int rcur = -1;
    float s_mine = 0.f;
    for (int pos = 0; pos < 64; ++pos) {
      int r = rl(srt_r, pos);
      if (r != rcur) {  // wave-uniform; ~7-8 reloads per task
        const float4* wr = S.w + (r << 10) + lane;
#pragma unroll
        for (int k = 0; k < 16; ++k) wv[k] = wr[k << 6];
#pragma unroll
        for (int k = 0; k < 16; ++k)
          asm volatile("" : "+v"(wv[k].x), "+v"(wv[k].y), "+v"(wv[k].z), "+v"(wv[k].w));
        rcur = r;
      }
      // fence: waits x(pos)'s write (issued last step-end, ~1 matvec old),
      // s_loads(pos) (also ~1 step old), and any wv reload just issued.
      asm volatile("s_waitcnt lgkmcnt(0)" ::: "memory");
      __builtin_amdgcn_wave_barrier();
      float acc = 0.f;
#pragma unroll
      for (int k = 0; k < 8; ++k) {  // d 0..31 via LDS broadcast reads
        float4 x = *(const float4*)(xbuf + 4 * k);
        acc = fmaf(wv[k].x, x.x, acc);
        acc = fmaf(wv[k].y, x.y, acc);
        acc = fmaf(wv[k].z, x.z, acc);
        acc = fmaf(wv[k].w, x.w, acc);
      }
#pragma unroll
      for (int k = 8; k < 16; ++k) {  // d 32..63 via SGPR operands
        acc = fmaf(wv[k].x, xu[k - 8].x, acc);
        acc = fmaf(wv[k].y, xu[k - 8].y, acc);
        acc = fmaf(wv[k].z, xu[k - 8].z, acc);
        acc = fmaf(wv[k].w, xu[k - 8].w, acc);
      }
      // write-ahead staging for pos+1 (in-order DS: executes after this
      // step's reads); then issue x(pos+2) and s_loads(pos+1).
      if (pos < 63) {
        __builtin_amdgcn_wave_barrier();
        xbuf[lane] = xin;  // compiler waits vmcnt for xin (1 step old)
        __builtin_amdgcn_wave_barrier();
        if (pos < 62) {
          int nbn2 = rl(srt_nb, pos + 2);
          xin = emb[((size_t)nbn2 << 6) + lane];
        }
        int nbn1 = rl(srt_nb, pos + 1);
        load_xu_hi(emb, nbn1, xu);
      }
      float y = tanhf(acc);
      float totv = wave_sum(u_e * y);
      int n = rl(order, pos);
      if (lane == n) s_mine = totv * (1.0f / 64.0f);
    }
    int seli[8];
    float w8[8];
    topsel_core(s_mine, lane, seli, w8);
    int nbs[8], rrs[8];
#pragma unroll
    for (int k = 0; k < 8; ++k) {
      int sk = __builtin_amdgcn_readfirstlane(seli[k]);
      nbs[k] = rl(nbr, sk);
      rrs[k] = rl(rel, sk);
    }
    float4 xtA[16], xtB[16];
    load_xu_full(emb, nbs[0], xtA);
    float agg = 0.f, labagg = 0.f;
#pragma unroll
    for (int k = 0; k < 8; ++k) {  // fully unrolled: xc/xn static per iter
      const float4* xc = (k & 1) ? xtB : xtA;
      float4* xn = (k & 1) ? xtA : xtB;
      if (k < 7) load_xu_full(emb, nbs[k + 1], xn);  // prefetch next selected
      float y = transform_pre(xc, rrs[k], lane, S.w);
      agg = fmaf(w8[k], y, agg);
      float raw2 = labels[(size_t)u * np1 + nbs[k]];  // uniform -> scalar load
      float lab2 = (nbs[k] != item) ? raw2 : 0.5f;
      labagg = fmaf(w8[k], lab2, labagg);
    }
    float base = emb1[((size_t)bj << 6) + lane];
    emb1p[((size_t)bj << 6) + lane] = fmaxf(fmaf(agg, 0.125f, base), 0.f);
    if (lane == 0) {
      float raw1 = labels[(size_t)u * np1 + eid];
      bool hm = (eid != item);
      float l1 = hm ? raw1 : 0.5f;
      bool reset1 = (raw1 != 0.5f) && hm;
      lab1p[bj] = reset1 ? l1 : labagg;
    }
  }
}

__global__ __launch_bounds__(256) void k_final(const int* __restrict__ ii,
                                               const float* __restrict__ emb,
                                               const float* __restrict__ user_emb,
                                               const float* __restrict__ s0,
                                               const float* __restrict__ emb1,
                                               const float* __restrict__ emb1p,
                                               const float* __restrict__ lab1p,
                                               float* __restrict__ out, int bs) {
  int w = threadIdx.x >> 6, lane = threadIdx.x & 63;
  int b = blockIdx.x * 4 + w;
  if (b >= bs) return;
  int item = ii[b];
  float ue = user_emb[((size_t)b << 6) + lane];
  float agg = 0.f, aggp = 0.f, lab = 0.f;
#pragma unroll
  for (int j = 0; j < 8; ++j) {
    float s = s0[b * 8 + j];
    agg = fmaf(s, emb1[(((size_t)b * 8 + j) << 6) + lane], agg);
    aggp = fmaf(s, emb1p[(((size_t)b * 8 + j) << 6) + lane], aggp);
    lab = fmaf(s, lab1p[b * 8 + j], lab);
  }
  float e0 = emb[((size_t)item << 6) + lane];
  float h = fmaxf(fmaf(agg, 0.125f, e0), 0.f);  // relu(agg01 + emb0)
  float h2 = tanhf(fmaf(aggp, 0.125f, h));      // tanh(agg01' + emb0')
  float dot = wave_sum(ue * h2);
  if (lane == 0) {
    out[b] = 1.f / (1.f + expf(-dot));
    out[bs + b] = 1.f / (1.f + expf(-(lab - 0.5f)));
  }
}

extern "C" void kernel_launch(void* const* d_in, const int* in_sizes, int n_in, void* d_out,
                              int out_size, void* d_ws, size_t ws_size, hipStream_t stream) {
  const int* ui = (const int*)d_in[0];
  const int* ii = (const int*)d_in[1];
  const float* emb = (const float*)d_in[2];
  const float* W = (const float*)d_in[3];
  const int* adjE = (const int*)d_in[4];
  const int* adjR = (const int*)d_in[5];
  const int* clicked = (const int*)d_in[6];
  const float* numc = (const float*)d_in[7];
  const float* labels = (const float*)d_in[8];

  int bs = in_sizes[0];
  int np1 = in_sizes[2] / 64;  // n_entity + 1 (= labels row stride = offset)
  int nuser = in_sizes[7];
  int hist = in_sizes[6] / nuser;

  // workspace layout
  float* user_emb = (float*)d_ws;               // bs*64
  float* s0w = user_emb + (size_t)bs * 64;      // bs*8
  int* e1 = (int*)(s0w + (size_t)bs * 8);       // bs*8
  float* emb1 = (float*)(e1 + (size_t)bs * 8);  // bs*8*64
  float* emb1p = emb1 + (size_t)bs * 8 * 64;    // bs*8*64
  float* lab1p = emb1p + (size_t)bs * 8 * 64;   // bs*8

  int nt0 = bs;      // hop0 tasks
  int nt1 = bs * 8;  // hop1 tasks

  k_user<<<(nt0 + 3) / 4, 256, 0, stream>>>(ui, emb, clicked, numc, hist, user_emb, nt0);
  k_hop0_f<<<256, NTHR, 0, stream>>>(ii, emb, W, adjE, adjR, user_emb, e1, s0w, emb1,
                                     nt0);
  k_hop1_f<<<256, NTHR, 0, stream>>>(ui, ii, emb, W, adjE, adjR, labels, np1, user_emb,
                                     e1, emb1, emb1p, lab1p, nt1);
  k_final<<<(nt0 + 3) / 4, 256, 0, stream>>>(ii, emb, user_emb, s0w, emb1, emb1p, lab1p,
                                             (float*)d_out, bs);
}